// Round 13
// baseline (11616.778 us; speedup 1.0000x reference)
//
#include <hip/hip_runtime.h>
#include <hip/hip_bf16.h>
#include <cmath>

// ---------------------------------------------------------------------------
// SelectiveMagnoViT forward. Round 12: persistent layers kernel.
// The 12-layer loop (48 dispatches) becomes ONE kernel launch: 512 blocks
// (guaranteed co-resident via __launch_bounds__(256,2)), phases grid-stride
// over their tile sets at full parallelism, separated by a manual
// device-scope grid barrier (flag array + generation, zeroed per call).
// Phase bodies are the round-5/11 kernels verbatim.
// ---------------------------------------------------------------------------

#define Bsz   64
#define NPATCH 576
#define KSEL  144
#define SEQ   145
#define DIM   192
#define HIDN  768
#define GRID  512

typedef __bf16 bf16x8 __attribute__((ext_vector_type(8)));
typedef float  f32x4  __attribute__((ext_vector_type(4)));

// ---------------- patch scores: 16x16 average pool of line drawing ----------
__global__ __launch_bounds__(256) void scores_kernel(const float* __restrict__ line,
                                                     float* __restrict__ scores)
{
    int gp = blockIdx.x;              // b*576 + p
    int b = gp / NPATCH, p = gp % NPATCH;
    int gy = p / 24, gx = p % 24;
    int t = threadIdx.x, py = t >> 4, px = t & 15;
    float v = line[((size_t)b * 384 + gy * 16 + py) * 384 + gx * 16 + px];
    for (int off = 32; off; off >>= 1) v += __shfl_xor(v, off);
    __shared__ float red[4];
    if ((t & 63) == 0) red[t >> 6] = v;
    __syncthreads();
    if (t == 0) scores[gp] = (red[0] + red[1] + red[2] + red[3]) * (1.f / 256.f);
}

// ---------------- exact top-k via rank scatter (jax order, no serial) -------
__global__ __launch_bounds__(256) void topk_kernel(const float* __restrict__ scores,
                                                   int* __restrict__ idx)
{
    int b = blockIdx.x;
    __shared__ float s[NPATCH];
    for (int i = threadIdx.x; i < NPATCH; i += 256) s[i] = scores[b * NPATCH + i];
    __syncthreads();
    for (int i = threadIdx.x; i < NPATCH; i += 256) {
        float si = s[i];
        int cnt = 0;
        for (int j = 0; j < NPATCH; ++j) {
            float sj = s[j];
            cnt += (sj > si) || (sj == si && j < i);
        }
        if (cnt < KSEL) idx[b * KSEL + cnt] = i;
    }
}

// ---------------- gather selected patches into bf16 (B*144, 768) ------------
__global__ __launch_bounds__(256) void gather_kernel(const float* __restrict__ magno,
                                                     const int* __restrict__ idx,
                                                     __hip_bfloat16* __restrict__ selp)
{
    int bs = blockIdx.x;              // b*144 + s
    int b = bs / KSEL;
    int pi = idx[bs];
    int gy = pi / 24, gx = pi % 24;
    int t = threadIdx.x, py = t >> 4, px = t & 15;
    size_t src = ((size_t)b * 3 * 384 + gy * 16 + py) * 384 + gx * 16 + px;
    __hip_bfloat16* dst = &selp[(size_t)bs * 768];
#pragma unroll
    for (int c = 0; c < 3; ++c)
        dst[c * 256 + t] = __float2bfloat16(magno[src + (size_t)c * 384 * 384]);
}

// ---------------- f32 -> bf16 elementwise (conv_w, already [N][K]) ----------
__global__ __launch_bounds__(256) void convert_bf16_kernel(const float* __restrict__ src,
                                                           __hip_bfloat16* __restrict__ dst,
                                                           int n)
{
    int i = blockIdx.x * 256 + threadIdx.x;
    if (i < n) dst[i] = __float2bfloat16(src[i]);
}

// ---------------- per-layer transpose+convert: src[l][R][C] -> dst[l][C][R] -
__global__ __launch_bounds__(256) void transpose_w_kernel(const float* __restrict__ src,
                                                          __hip_bfloat16* __restrict__ dst,
                                                          int R, int C)
{
    __shared__ float t[32][33];
    size_t lo = (size_t)blockIdx.z * R * C;
    int r0 = blockIdx.y * 32, c0 = blockIdx.x * 32;
    int tx = threadIdx.x & 31, ty = threadIdx.x >> 5;   // 8 rows per pass
#pragma unroll
    for (int i = 0; i < 32; i += 8)
        t[ty + i][tx] = src[lo + (size_t)(r0 + ty + i) * C + c0 + tx];
    __syncthreads();
#pragma unroll
    for (int i = 0; i < 32; i += 8)
        dst[lo + (size_t)(c0 + ty + i) * R + r0 + tx] = __float2bfloat16(t[tx][ty + i]);
}

// ---------------- cls token init --------------------------------------------
__global__ void cls_kernel(const float* __restrict__ cls, const float* __restrict__ pos,
                           float* __restrict__ h)
{
    int b = blockIdx.x, t = threadIdx.x;      // 192 threads
    h[(size_t)b * SEQ * DIM + t] = cls[t] + pos[t];
}

// ---------------- LayerNorm over D=192 -> bf16 out (layer-0 ln1 only) -------
__global__ __launch_bounds__(256) void ln_kernel(const float* __restrict__ x,
                                                 const float* __restrict__ s,
                                                 const float* __restrict__ bia,
                                                 __hip_bfloat16* __restrict__ y, int ntok)
{
    int w = threadIdx.x >> 6, lane = threadIdx.x & 63;
    int tok = blockIdx.x * 4 + w;
    if (tok >= ntok) return;
    const float* xp = &x[(size_t)tok * DIM];
    float x0 = xp[lane], x1 = xp[lane + 64], x2 = xp[lane + 128];
    float sum = x0 + x1 + x2;
    for (int off = 32; off; off >>= 1) sum += __shfl_xor(sum, off);
    float mean = sum * (1.f / 192.f);
    float d0 = x0 - mean, d1 = x1 - mean, d2 = x2 - mean;
    float vs = d0 * d0 + d1 * d1 + d2 * d2;
    for (int off = 32; off; off >>= 1) vs += __shfl_xor(vs, off);
    float rs = rsqrtf(vs * (1.f / 192.f) + 1e-6f);
    __hip_bfloat16* yp = &y[(size_t)tok * DIM];
    yp[lane]       = __float2bfloat16(d0 * rs * s[lane]       + bia[lane]);
    yp[lane + 64]  = __float2bfloat16(d1 * rs * s[lane + 64]  + bia[lane + 64]);
    yp[lane + 128] = __float2bfloat16(d2 * rs * s[lane + 128] + bia[lane + 128]);
}

// ---------------- patch-embed GEMM (prologue, standalone) -------------------
__global__ __launch_bounds__(256) void gemm_embed(const __hip_bfloat16* __restrict__ A,
                                                  const __hip_bfloat16* __restrict__ Wt,
                                                  const float* __restrict__ bias,
                                                  float* __restrict__ h,
                                                  int K,
                                                  const int* __restrict__ selidx,
                                                  const float* __restrict__ pos)
{
    __shared__ __align__(16) char As[8192];
    __shared__ __align__(16) char Bs[8192];
    const int tid = threadIdx.x;
    const int lane = tid & 63, wid = tid >> 6;
    const int wr = wid >> 1, wc = wid & 1;
    const int lr = lane & 15, lk = lane >> 4;
    const int m0 = blockIdx.y * 64, n0 = blockIdx.x * 64;
    f32x4 acc[2][2] = {};

    for (int k0 = 0; k0 < K; k0 += 64) {
#pragma unroll
        for (int it = 0; it < 2; ++it) {
            int chunk = it * 256 + tid;
            int r = chunk >> 3, g = chunk & 7;
            int loff = r * 128 + ((g ^ (r & 7)) * 16);
            *reinterpret_cast<uint4*>(As + loff) =
                *reinterpret_cast<const uint4*>(&A[(size_t)(m0 + r) * K + k0 + g * 8]);
            *reinterpret_cast<uint4*>(Bs + loff) =
                *reinterpret_cast<const uint4*>(&Wt[(size_t)(n0 + r) * K + k0 + g * 8]);
        }
        __syncthreads();
#pragma unroll
        for (int kc = 0; kc < 2; ++kc) {
            int g = kc * 4 + lk;
            bf16x8 af[2], bfr[2];
#pragma unroll
            for (int mi = 0; mi < 2; ++mi) {
                int r = wr * 32 + mi * 16 + lr;
                af[mi] = *reinterpret_cast<const bf16x8*>(As + r * 128 + ((g ^ (r & 7)) * 16));
            }
#pragma unroll
            for (int ni = 0; ni < 2; ++ni) {
                int r = wc * 32 + ni * 16 + lr;
                bfr[ni] = *reinterpret_cast<const bf16x8*>(Bs + r * 128 + ((g ^ (r & 7)) * 16));
            }
#pragma unroll
            for (int mi = 0; mi < 2; ++mi)
#pragma unroll
                for (int ni = 0; ni < 2; ++ni)
                    acc[mi][ni] = __builtin_amdgcn_mfma_f32_16x16x32_bf16(
                        af[mi], bfr[ni], acc[mi][ni], 0, 0, 0);
        }
        __syncthreads();
    }

#pragma unroll
    for (int mi = 0; mi < 2; ++mi)
#pragma unroll
    for (int ni = 0; ni < 2; ++ni)
#pragma unroll
    for (int j = 0; j < 4; ++j) {
        int row = m0 + wr * 32 + mi * 16 + (lane >> 4) * 4 + j;
        int col = n0 + wc * 32 + ni * 16 + (lane & 15);
        float v = acc[mi][ni][j] + bias[col];
        int bb2 = row / KSEL, ss = row % KSEL;
        int pi = selidx[row];
        v += pos[(size_t)(1 + pi) * DIM + col];
        h[((size_t)bb2 * SEQ + 1 + ss) * DIM + col] = v;
    }
}

// ===================== persistent layers kernel ==============================

// manual grid barrier: per-block flag stores + block-0 scan + gen publish.
// Safe because GRID=512 blocks are guaranteed co-resident (2 blocks/CU via
// __launch_bounds__(256,2): VGPR<=256, LDS 32KB<=80KB, 8 waves<=32/CU).
__device__ __forceinline__ void grid_barrier(unsigned* flags, unsigned* gen,
                                             unsigned epoch)
{
    __syncthreads();
    __threadfence();
    if (blockIdx.x == 0) {
        for (int i = threadIdx.x; i < GRID; i += 256) {
            if (i == 0) continue;
            while (__hip_atomic_load(&flags[i], __ATOMIC_ACQUIRE,
                                     __HIP_MEMORY_SCOPE_AGENT) < epoch)
                __builtin_amdgcn_s_sleep(1);
        }
        __syncthreads();
        if (threadIdx.x == 0)
            __hip_atomic_store(gen, epoch, __ATOMIC_RELEASE, __HIP_MEMORY_SCOPE_AGENT);
    } else {
        if (threadIdx.x == 0) {
            __hip_atomic_store(&flags[blockIdx.x], epoch, __ATOMIC_RELEASE,
                               __HIP_MEMORY_SCOPE_AGENT);
            while (__hip_atomic_load(gen, __ATOMIC_ACQUIRE,
                                     __HIP_MEMORY_SCOPE_AGENT) < epoch)
                __builtin_amdgcn_s_sleep(1);
        }
    }
    __syncthreads();
    __threadfence();
}

// ---- phase 1: qkv GEMM tile (9 x 145); cols<384 -> qk; >=384 -> Vt^T -------
__device__ void dev_qkv(int tile, const __hip_bfloat16* A, const __hip_bfloat16* Wt,
                        const float* bias, __hip_bfloat16* qk, __hip_bfloat16* Vt,
                        char* As, char* Bs)
{
    const int tid = threadIdx.x;
    const int lane = tid & 63, wid = tid >> 6;
    const int wr = wid >> 1, wc = wid & 1;
    const int lr = lane & 15, lk = lane >> 4;
    const int m0 = (tile / 9) * 64, n0 = (tile % 9) * 64;
    const int K = DIM;
    f32x4 acc[2][2] = {};

    for (int k0 = 0; k0 < K; k0 += 64) {
#pragma unroll
        for (int it = 0; it < 2; ++it) {
            int chunk = it * 256 + tid;
            int r = chunk >> 3, g = chunk & 7;
            int loff = r * 128 + ((g ^ (r & 7)) * 16);
            *reinterpret_cast<uint4*>(As + loff) =
                *reinterpret_cast<const uint4*>(&A[(size_t)(m0 + r) * K + k0 + g * 8]);
            *reinterpret_cast<uint4*>(Bs + loff) =
                *reinterpret_cast<const uint4*>(&Wt[(size_t)(n0 + r) * K + k0 + g * 8]);
        }
        __syncthreads();
#pragma unroll
        for (int kc = 0; kc < 2; ++kc) {
            int g = kc * 4 + lk;
            bf16x8 af[2], bfr[2];
#pragma unroll
            for (int mi = 0; mi < 2; ++mi) {
                int r = wr * 32 + mi * 16 + lr;
                af[mi] = *reinterpret_cast<const bf16x8*>(As + r * 128 + ((g ^ (r & 7)) * 16));
            }
#pragma unroll
            for (int ni = 0; ni < 2; ++ni) {
                int r = wc * 32 + ni * 16 + lr;
                bfr[ni] = *reinterpret_cast<const bf16x8*>(Bs + r * 128 + ((g ^ (r & 7)) * 16));
            }
#pragma unroll
            for (int mi = 0; mi < 2; ++mi)
#pragma unroll
                for (int ni = 0; ni < 2; ++ni)
                    acc[mi][ni] = __builtin_amdgcn_mfma_f32_16x16x32_bf16(
                        af[mi], bfr[ni], acc[mi][ni], 0, 0, 0);
        }
        __syncthreads();
    }

#pragma unroll
    for (int mi = 0; mi < 2; ++mi)
#pragma unroll
    for (int ni = 0; ni < 2; ++ni)
#pragma unroll
    for (int j = 0; j < 4; ++j) {
        int row = m0 + wr * 32 + mi * 16 + (lane >> 4) * 4 + j;
        int col = n0 + wc * 32 + ni * 16 + (lane & 15);
        float v = acc[mi][ni][j] + bias[col];
        if (col < 384) {
            qk[(size_t)row * 384 + col] = __float2bfloat16(v);
        } else {
            int c = col - 384;
            int b = row / SEQ, s = row - b * SEQ;
            Vt[((size_t)(b * 3 + (c >> 6)) * 64 + (c & 63)) * 160 + s] = __float2bfloat16(v);
        }
    }
}

// ---- phase 2: attn + proj + res + ln2, 16-query tile (10 x 64) -------------
__device__ void dev_attnproj(int tile, const __hip_bfloat16* qk,
                             const __hip_bfloat16* Vt, const __hip_bfloat16* Wp,
                             const float* pbias, float* h,
                             const float* ls, const float* lb,
                             __hip_bfloat16* y, char* LDS)
{
    const int b = tile / 10, qt = tile % 10;
    const int tid = threadIdx.x;
    const int w = tid >> 6, lane = tid & 63;
    const int lr = lane & 15, lg = lane >> 4;
    __hip_bfloat16* Ps = (__hip_bfloat16*)LDS;              // [3][16][168] = 16128 B
    __hip_bfloat16* Ot = (__hip_bfloat16*)(LDS + 16128);    // [16][200]    =  6400 B
    float* redsum = (float*)(LDS + 22528);                  // [4][16]
    float* redsq  = (float*)(LDS + 22784);                  // [4][16]

    const size_t qbase = (size_t)b * SEQ * 384;
    const int q0 = qt * 16;

    if (w < 3) {
        const int hh = w;
        bf16x8 aq[2];
#pragma unroll
        for (int ks = 0; ks < 2; ++ks)
            aq[ks] = *reinterpret_cast<const bf16x8*>(
                &qk[qbase + (size_t)(q0 + lr) * 384 + hh * 64 + ks * 32 + lg * 8]);
        f32x4 sc[10] = {};
#pragma unroll
        for (int nf = 0; nf < 10; ++nf) {
            int key = nf * 16 + lr;
#pragma unroll
            for (int ks = 0; ks < 2; ++ks) {
                bf16x8 bk = *reinterpret_cast<const bf16x8*>(
                    &qk[qbase + (size_t)key * 384 + 192 + hh * 64 + ks * 32 + lg * 8]);
                sc[nf] = __builtin_amdgcn_mfma_f32_16x16x32_bf16(aq[ks], bk, sc[nf], 0, 0, 0);
            }
        }
        float mx[4] = {-1e30f, -1e30f, -1e30f, -1e30f};
#pragma unroll
        for (int nf = 0; nf < 10; ++nf) {
            bool valid = nf * 16 + lr < SEQ;
#pragma unroll
            for (int j = 0; j < 4; ++j) {
                float v = valid ? sc[nf][j] * 0.125f : -1e30f;
                sc[nf][j] = v;
                mx[j] = fmaxf(mx[j], v);
            }
        }
#pragma unroll
        for (int j = 0; j < 4; ++j)
            for (int off = 1; off < 16; off <<= 1)
                mx[j] = fmaxf(mx[j], __shfl_xor(mx[j], off));
        float sm[4] = {0.f, 0.f, 0.f, 0.f};
#pragma unroll
        for (int nf = 0; nf < 10; ++nf)
#pragma unroll
            for (int j = 0; j < 4; ++j) {
                float p = __expf(sc[nf][j] - mx[j]);
                sc[nf][j] = p;
                sm[j] += p;
            }
#pragma unroll
        for (int j = 0; j < 4; ++j) {
            for (int off = 1; off < 16; off <<= 1) sm[j] += __shfl_xor(sm[j], off);
            sm[j] = 1.f / sm[j];
        }
#pragma unroll
        for (int nf = 0; nf < 10; ++nf) {
            int key = nf * 16 + lr;
#pragma unroll
            for (int j = 0; j < 4; ++j)
                Ps[(hh * 16 + lg * 4 + j) * 168 + key] = __float2bfloat16(sc[nf][j] * sm[j]);
        }
        const __hip_bfloat16* vtb = &Vt[(size_t)(b * 3 + hh) * 64 * 160];
        f32x4 oacc[4] = {};
#pragma unroll
        for (int ks = 0; ks < 5; ++ks) {
            bf16x8 ap = *reinterpret_cast<const bf16x8*>(&Ps[(hh * 16 + lr) * 168 + ks * 32 + lg * 8]);
#pragma unroll
            for (int nf = 0; nf < 4; ++nf) {
                bf16x8 bv = *reinterpret_cast<const bf16x8*>(
                    &vtb[(size_t)(nf * 16 + lr) * 160 + ks * 32 + lg * 8]);
                oacc[nf] = __builtin_amdgcn_mfma_f32_16x16x32_bf16(ap, bv, oacc[nf], 0, 0, 0);
            }
        }
#pragma unroll
        for (int nf = 0; nf < 4; ++nf)
#pragma unroll
            for (int j = 0; j < 4; ++j)
                Ot[(lg * 4 + j) * 200 + hh * 64 + nf * 16 + lr] = __float2bfloat16(oacc[nf][j]);
    }
    __syncthreads();

    const int wn = w;
    f32x4 pacc[3] = {};
#pragma unroll
    for (int kk = 0; kk < 6; ++kk) {
        bf16x8 af = *reinterpret_cast<const bf16x8*>(&Ot[lr * 200 + kk * 32 + lg * 8]);
#pragma unroll
        for (int nf = 0; nf < 3; ++nf) {
            int ncol = wn * 48 + nf * 16 + lr;
            bf16x8 bw = *reinterpret_cast<const bf16x8*>(&Wp[(size_t)ncol * 192 + kk * 32 + lg * 8]);
            pacc[nf] = __builtin_amdgcn_mfma_f32_16x16x32_bf16(af, bw, pacc[nf], 0, 0, 0);
        }
    }
    float v[3][4];
    float psum[4] = {}, psq[4] = {};
#pragma unroll
    for (int nf = 0; nf < 3; ++nf) {
        int col = wn * 48 + nf * 16 + lr;
        float bcol = pbias[col];
#pragma unroll
        for (int j = 0; j < 4; ++j) {
            int q = q0 + lg * 4 + j;
            float res = (q < SEQ) ? h[((size_t)b * SEQ + q) * DIM + col] : 0.f;
            float t = pacc[nf][j] + bcol + res;
            v[nf][j] = t;
            psum[j] += t;
            psq[j] += t * t;
        }
    }
#pragma unroll
    for (int j = 0; j < 4; ++j) {
        for (int off = 1; off < 16; off <<= 1) {
            psum[j] += __shfl_xor(psum[j], off);
            psq[j]  += __shfl_xor(psq[j], off);
        }
        if (lr == 0) {
            redsum[wn * 16 + lg * 4 + j] = psum[j];
            redsq[wn * 16 + lg * 4 + j]  = psq[j];
        }
    }
    __syncthreads();
#pragma unroll
    for (int j = 0; j < 4; ++j) {
        int r = lg * 4 + j;
        int q = q0 + r;
        if (q >= SEQ) continue;
        float tsum = redsum[r] + redsum[16 + r] + redsum[32 + r] + redsum[48 + r];
        float tsq  = redsq[r]  + redsq[16 + r]  + redsq[32 + r]  + redsq[48 + r];
        float mean = tsum * (1.f / 192.f);
        float var  = tsq * (1.f / 192.f) - mean * mean;
        float rs = rsqrtf(var + 1e-6f);
#pragma unroll
        for (int nf = 0; nf < 3; ++nf) {
            int col = wn * 48 + nf * 16 + lr;
            float t = v[nf][j];
            h[((size_t)b * SEQ + q) * DIM + col] = t;
            y[((size_t)b * SEQ + q) * DIM + col] =
                __float2bfloat16((t - mean) * rs * ls[col] + lb[col]);
        }
    }
}

// ---- phase 3: fc1 GEMM + gelu tile (12 x 145) ------------------------------
__device__ void dev_fc1(int tile, const __hip_bfloat16* A, const __hip_bfloat16* Wt,
                        const float* bias, __hip_bfloat16* Cout, char* As, char* Bs)
{
    const int tid = threadIdx.x;
    const int lane = tid & 63, wid = tid >> 6;
    const int wr = wid >> 1, wc = wid & 1;
    const int lr = lane & 15, lk = lane >> 4;
    const int m0 = (tile / 12) * 64, n0 = (tile % 12) * 64;
    const int K = DIM, N = HIDN;
    f32x4 acc[2][2] = {};

    for (int k0 = 0; k0 < K; k0 += 64) {
#pragma unroll
        for (int it = 0; it < 2; ++it) {
            int chunk = it * 256 + tid;
            int r = chunk >> 3, g = chunk & 7;
            int loff = r * 128 + ((g ^ (r & 7)) * 16);
            *reinterpret_cast<uint4*>(As + loff) =
                *reinterpret_cast<const uint4*>(&A[(size_t)(m0 + r) * K + k0 + g * 8]);
            *reinterpret_cast<uint4*>(Bs + loff) =
                *reinterpret_cast<const uint4*>(&Wt[(size_t)(n0 + r) * K + k0 + g * 8]);
        }
        __syncthreads();
#pragma unroll
        for (int kc = 0; kc < 2; ++kc) {
            int g = kc * 4 + lk;
            bf16x8 af[2], bfr[2];
#pragma unroll
            for (int mi = 0; mi < 2; ++mi) {
                int r = wr * 32 + mi * 16 + lr;
                af[mi] = *reinterpret_cast<const bf16x8*>(As + r * 128 + ((g ^ (r & 7)) * 16));
            }
#pragma unroll
            for (int ni = 0; ni < 2; ++ni) {
                int r = wc * 32 + ni * 16 + lr;
                bfr[ni] = *reinterpret_cast<const bf16x8*>(Bs + r * 128 + ((g ^ (r & 7)) * 16));
            }
#pragma unroll
            for (int mi = 0; mi < 2; ++mi)
#pragma unroll
                for (int ni = 0; ni < 2; ++ni)
                    acc[mi][ni] = __builtin_amdgcn_mfma_f32_16x16x32_bf16(
                        af[mi], bfr[ni], acc[mi][ni], 0, 0, 0);
        }
        __syncthreads();
    }

#pragma unroll
    for (int mi = 0; mi < 2; ++mi)
#pragma unroll
    for (int ni = 0; ni < 2; ++ni)
#pragma unroll
    for (int j = 0; j < 4; ++j) {
        int row = m0 + wr * 32 + mi * 16 + (lane >> 4) * 4 + j;
        int col = n0 + wc * 32 + ni * 16 + (lane & 15);
        float v = acc[mi][ni][j] + bias[col];
        Cout[(size_t)row * N + col] =
            __float2bfloat16(0.5f * v * (1.f + erff(v * 0.70710678118654752f)));
    }
}

// ---- phase 4: fc2 + bias + residual (+LN) tile (145) -----------------------
__device__ void dev_resln(int tile, const __hip_bfloat16* A, const __hip_bfloat16* Wt,
                          const float* bias, float* h, const float* ls,
                          const float* lb, __hip_bfloat16* y, bool do_ln,
                          char* As, char* Bs)
{
    const int tid = threadIdx.x;
    const int lane = tid & 63, w = tid >> 6;
    const int lr = lane & 15, lg = lane >> 4;
    const int m0 = tile * 64;
    const int K = HIDN;
    f32x4 acc[12] = {};

    for (int k0 = 0; k0 < K; k0 += 64) {
        {
            int chunk = tid;
#pragma unroll
            for (int it = 0; it < 2; ++it, chunk += 256) {
                int r = chunk >> 3, g = chunk & 7;
                *reinterpret_cast<uint4*>(As + r * 128 + ((g ^ (r & 7)) * 16)) =
                    *reinterpret_cast<const uint4*>(&A[(size_t)(m0 + r) * K + k0 + g * 8]);
            }
        }
        {
            int chunk = tid;
#pragma unroll
            for (int it = 0; it < 6; ++it, chunk += 256) {
                int r = chunk >> 3, g = chunk & 7;
                *reinterpret_cast<uint4*>(Bs + r * 128 + ((g ^ (r & 7)) * 16)) =
                    *reinterpret_cast<const uint4*>(&Wt[(size_t)r * K + k0 + g * 8]);
            }
        }
        __syncthreads();
#pragma unroll
        for (int kc = 0; kc < 2; ++kc) {
            int g = kc * 4 + lg;
            int ar = w * 16 + lr;
            bf16x8 af = *reinterpret_cast<const bf16x8*>(As + ar * 128 + ((g ^ (ar & 7)) * 16));
#pragma unroll
            for (int nf = 0; nf < 12; ++nf) {
                int br = nf * 16 + lr;
                bf16x8 bfv = *reinterpret_cast<const bf16x8*>(Bs + br * 128 + ((g ^ (br & 7)) * 16));
                acc[nf] = __builtin_amdgcn_mfma_f32_16x16x32_bf16(af, bfv, acc[nf], 0, 0, 0);
            }
        }
        __syncthreads();
    }

    float v[12][4];
    float sum[4] = {0.f, 0.f, 0.f, 0.f};
#pragma unroll
    for (int nf = 0; nf < 12; ++nf) {
        int col = nf * 16 + lr;
#pragma unroll
        for (int j = 0; j < 4; ++j) {
            int row = m0 + w * 16 + lg * 4 + j;
            float t = acc[nf][j] + bias[col] + h[(size_t)row * DIM + col];
            v[nf][j] = t;
            h[(size_t)row * DIM + col] = t;
            sum[j] += t;
        }
    }
    if (do_ln) {
#pragma unroll
        for (int j = 0; j < 4; ++j)
            for (int off = 1; off < 16; off <<= 1) sum[j] += __shfl_xor(sum[j], off);
        float mean[4], sq[4] = {0.f, 0.f, 0.f, 0.f};
#pragma unroll
        for (int j = 0; j < 4; ++j) mean[j] = sum[j] * (1.f / 192.f);
#pragma unroll
        for (int nf = 0; nf < 12; ++nf)
#pragma unroll
            for (int j = 0; j < 4; ++j) {
                float d = v[nf][j] - mean[j];
                sq[j] += d * d;
            }
#pragma unroll
        for (int j = 0; j < 4; ++j) {
            for (int off = 1; off < 16; off <<= 1) sq[j] += __shfl_xor(sq[j], off);
            sq[j] = rsqrtf(sq[j] * (1.f / 192.f) + 1e-6f);
        }
#pragma unroll
        for (int nf = 0; nf < 12; ++nf) {
            int col = nf * 16 + lr;
            float sc = ls[col], bc = lb[col];
#pragma unroll
            for (int j = 0; j < 4; ++j) {
                int row = m0 + w * 16 + lg * 4 + j;
                y[(size_t)row * DIM + col] =
                    __float2bfloat16((v[nf][j] - mean[j]) * sq[j] * sc + bc);
            }
        }
    }
}

// ---- the persistent kernel -------------------------------------------------
__global__ __launch_bounds__(256, 2) void layers_kernel(
    __hip_bfloat16* y, __hip_bfloat16* qk, __hip_bfloat16* Vt,
    __hip_bfloat16* tbuf, float* h,
    const __hip_bfloat16* wt_qkv, const float* qkv_b,
    const __hip_bfloat16* wt_proj, const float* proj_b,
    const __hip_bfloat16* wt_fc1, const float* fc1_b,
    const __hip_bfloat16* wt_fc2, const float* fc2_b,
    const float* ln1_s, const float* ln1_b,
    const float* ln2_s, const float* ln2_b,
    unsigned* flags, unsigned* gen)
{
    __shared__ __align__(16) char LDS[32768];
    unsigned epoch = 0;

    for (int l = 0; l < 12; ++l) {
        const __hip_bfloat16* wq = wt_qkv + (size_t)l * 576 * DIM;
        const __hip_bfloat16* wp = wt_proj + (size_t)l * DIM * DIM;
        const __hip_bfloat16* w1 = wt_fc1 + (size_t)l * HIDN * DIM;
        const __hip_bfloat16* w2 = wt_fc2 + (size_t)l * DIM * HIDN;

        for (int t = blockIdx.x; t < 9 * 145; t += GRID)
            dev_qkv(t, y, wq, qkv_b + l * 576, qk, Vt, LDS, LDS + 8192);
        grid_barrier(flags, gen, ++epoch);

        for (int t = blockIdx.x; t < 10 * Bsz; t += GRID)
            dev_attnproj(t, qk, Vt, wp, proj_b + l * DIM, h,
                         ln2_s + l * DIM, ln2_b + l * DIM, y, LDS);
        grid_barrier(flags, gen, ++epoch);

        for (int t = blockIdx.x; t < 12 * 145; t += GRID)
            dev_fc1(t, y, w1, fc1_b + l * HIDN, tbuf, LDS, LDS + 8192);
        grid_barrier(flags, gen, ++epoch);

        for (int t = blockIdx.x; t < 145; t += GRID)
            dev_resln(t, tbuf, w2, fc2_b + l * DIM, h,
                      ln1_s + (l + 1) * DIM, ln1_b + (l + 1) * DIM, y,
                      l < 11, LDS, LDS + 8192);
        if (l != 11)
            grid_barrier(flags, gen, ++epoch);
    }
}

// ---------------- head: final LN of cls + (64,192)@(192,1000) ---------------
__global__ __launch_bounds__(256) void head_kernel(const float* __restrict__ h,
                                                   const float* __restrict__ nfs,
                                                   const float* __restrict__ nfb,
                                                   const float* __restrict__ hw,
                                                   const float* __restrict__ hb,
                                                   float* __restrict__ out)
{
    int b = blockIdx.x, t = threadIdx.x;
    __shared__ float y[DIM];
    __shared__ float red[4];
    float x = (t < DIM) ? h[(size_t)b * SEQ * DIM + t] : 0.f;
    float sum = x;
    for (int off = 32; off; off >>= 1) sum += __shfl_xor(sum, off);
    if ((t & 63) == 0) red[t >> 6] = sum;
    __syncthreads();
    float mean = (red[0] + red[1] + red[2] + red[3]) * (1.f / 192.f);
    __syncthreads();
    float d = (t < DIM) ? (x - mean) : 0.f;
    float v = d * d;
    for (int off = 32; off; off >>= 1) v += __shfl_xor(v, off);
    if ((t & 63) == 0) red[t >> 6] = v;
    __syncthreads();
    float var = (red[0] + red[1] + red[2] + red[3]) * (1.f / 192.f);
    float rs = rsqrtf(var + 1e-6f);
    if (t < DIM) y[t] = d * rs * nfs[t] + nfb[t];
    __syncthreads();
    for (int n = t; n < 1000; n += 256) {
        float acc = hb[n];
#pragma unroll 8
        for (int k = 0; k < DIM; ++k)
            acc = fmaf(y[k], hw[(size_t)k * 1000 + n], acc);
        out[(size_t)b * 1000 + n] = acc;
    }
}

// ---------------------------------------------------------------------------
extern "C" void kernel_launch(void* const* d_in, const int* in_sizes, int n_in,
                              void* d_out, int out_size, void* d_ws, size_t ws_size,
                              hipStream_t stream)
{
    const float* magno  = (const float*)d_in[0];
    const float* line   = (const float*)d_in[1];
    const float* conv_w = (const float*)d_in[2];
    const float* conv_b = (const float*)d_in[3];
    const float* pos    = (const float*)d_in[4];
    const float* cls    = (const float*)d_in[5];
    const float* ln1_s  = (const float*)d_in[6];
    const float* ln1_b  = (const float*)d_in[7];
    const float* qkv_w  = (const float*)d_in[8];
    const float* qkv_b  = (const float*)d_in[9];
    const float* proj_w = (const float*)d_in[10];
    const float* proj_b = (const float*)d_in[11];
    const float* ln2_s  = (const float*)d_in[12];
    const float* ln2_b  = (const float*)d_in[13];
    const float* fc1_w  = (const float*)d_in[14];
    const float* fc1_b  = (const float*)d_in[15];
    const float* fc2_w  = (const float*)d_in[16];
    const float* fc2_b  = (const float*)d_in[17];
    const float* normf_s = (const float*)d_in[18];
    const float* normf_b = (const float*)d_in[19];
    const float* head_w = (const float*)d_in[20];
    const float* head_b = (const float*)d_in[21];
    float* out = (float*)d_out;
    (void)in_sizes; (void)n_in; (void)out_size; (void)ws_size;

    // workspace layout (bytes)
    char* ws = (char*)d_ws;
    int*            idx     = (int*)            (ws + 0);         //    36864
    unsigned*       barrier = (unsigned*)       (ws + 40960);     //     4096 (flags+gen)
    float*          h       = (float*)          (ws + 147456);    //  7127040
    __hip_bfloat16* y       = (__hip_bfloat16*) (ws + 7274496);   //  3563520
    __hip_bfloat16* qk      = (__hip_bfloat16*) (ws + 10838016);  //  7127040
    __hip_bfloat16* Vt      = (__hip_bfloat16*) (ws + 17965056);  //  3932160
    __hip_bfloat16* tbuf    = (__hip_bfloat16*) (ws + 21897216);  // 14254080
    __hip_bfloat16* wt_qkv  = (__hip_bfloat16*) (ws + 36151296);  //  2654208
    __hip_bfloat16* wt_proj = (__hip_bfloat16*) (ws + 38805504);  //   884736
    __hip_bfloat16* wt_fc1  = (__hip_bfloat16*) (ws + 39690240);  //  3538944
    __hip_bfloat16* wt_fc2  = (__hip_bfloat16*) (ws + 43229184);  //  3538944
    float*          scoresbuf = (float*)qk;             // alias (used before qk)
    __hip_bfloat16* convT     = y;                      // alias (used before y)
    __hip_bfloat16* selp      = tbuf;                   // alias

    unsigned* flags = barrier;            // [GRID]
    unsigned* gen   = barrier + GRID;

    // ---- prep: zero barrier state + Vt pads; weights -> bf16 [N][K] ----
    hipMemsetAsync(barrier, 0, 4096, stream);
    hipMemsetAsync(Vt, 0, 3932160, stream);
    transpose_w_kernel<<<dim3(18, 6, 12), 256, 0, stream>>>(qkv_w, wt_qkv, DIM, 576);
    transpose_w_kernel<<<dim3(6, 6, 12),  256, 0, stream>>>(proj_w, wt_proj, DIM, DIM);
    transpose_w_kernel<<<dim3(24, 6, 12), 256, 0, stream>>>(fc1_w, wt_fc1, DIM, HIDN);
    transpose_w_kernel<<<dim3(6, 24, 12), 256, 0, stream>>>(fc2_w, wt_fc2, HIDN, DIM);
    convert_bf16_kernel<<<576, 256, 0, stream>>>(conv_w, convT, DIM * 768);

    // ---- patch selection + embed ----
    scores_kernel<<<Bsz * NPATCH, 256, 0, stream>>>(line, scoresbuf);
    topk_kernel<<<Bsz, 256, 0, stream>>>(scoresbuf, idx);
    gather_kernel<<<Bsz * KSEL, 256, 0, stream>>>(magno, idx, selp);
    cls_kernel<<<Bsz, DIM, 0, stream>>>(cls, pos, h);
    gemm_embed<<<dim3(3, 144), 256, 0, stream>>>(selp, convT, conv_b, h,
                                                 768, idx, pos);

    const int ntok = Bsz * SEQ;              // 9280 = 145*64
    ln_kernel<<<ntok / 4, 256, 0, stream>>>(h, ln1_s, ln1_b, y, ntok);

    // ---- all 12 layers in one persistent dispatch ----
    layers_kernel<<<GRID, 256, 0, stream>>>(y, qk, Vt, tbuf, h,
                                            wt_qkv, qkv_b, wt_proj, proj_b,
                                            wt_fc1, fc1_b, wt_fc2, fc2_b,
                                            ln1_s, ln1_b, ln2_s, ln2_b,
                                            flags, gen);

    head_kernel<<<Bsz, 256, 0, stream>>>(h, normf_s, normf_b, head_w, head_b, out);
}

// Round 14
// 925.984 us; speedup vs baseline: 12.5453x; 12.5453x over previous
//
#include <hip/hip_runtime.h>
#include <hip/hip_bf16.h>
#include <cmath>

// ---------------------------------------------------------------------------
// SelectiveMagnoViT forward. Round 13: round-5 structure (best 941us) with
// prologue consolidation: one fused weight-prep kernel (was 5 dispatches),
// scores at 4 patches/block (grid 36864 -> 9216). Layer loop unchanged.
// ---------------------------------------------------------------------------

#define Bsz   64
#define NPATCH 576
#define KSEL  144
#define SEQ   145
#define DIM   192
#define HIDN  768

typedef __bf16 bf16x8 __attribute__((ext_vector_type(8)));
typedef float  f32x4  __attribute__((ext_vector_type(4)));

// ---------------- patch scores: wave = patch, lane reads float4 -------------
__global__ __launch_bounds__(256) void scores_kernel(const float* __restrict__ line,
                                                     float* __restrict__ scores)
{
    int gp = blockIdx.x * 4 + (threadIdx.x >> 6);   // global patch id
    int lane = threadIdx.x & 63;
    int b = gp / NPATCH, p = gp % NPATCH;
    int gy = p / 24, gx = p % 24;
    const float* base = &line[((size_t)b * 384 + gy * 16 + (lane >> 2)) * 384
                              + gx * 16 + (lane & 3) * 4];
    float4 v = *reinterpret_cast<const float4*>(base);
    float s = v.x + v.y + v.z + v.w;
    for (int off = 32; off; off >>= 1) s += __shfl_xor(s, off);
    if (lane == 0) scores[gp] = s * (1.f / 256.f);
}

// ---------------- exact top-k via rank scatter (jax order, no serial) -------
__global__ __launch_bounds__(256) void topk_kernel(const float* __restrict__ scores,
                                                   int* __restrict__ idx)
{
    int b = blockIdx.x;
    __shared__ float s[NPATCH];
    for (int i = threadIdx.x; i < NPATCH; i += 256) s[i] = scores[b * NPATCH + i];
    __syncthreads();
    for (int i = threadIdx.x; i < NPATCH; i += 256) {
        float si = s[i];
        int cnt = 0;
        for (int j = 0; j < NPATCH; ++j) {
            float sj = s[j];
            cnt += (sj > si) || (sj == si && j < i);
        }
        if (cnt < KSEL) idx[b * KSEL + cnt] = i;
    }
}

// ---------------- gather selected patches into bf16 (B*144, 768) ------------
__global__ __launch_bounds__(256) void gather_kernel(const float* __restrict__ magno,
                                                     const int* __restrict__ idx,
                                                     __hip_bfloat16* __restrict__ selp)
{
    int bs = blockIdx.x;              // b*144 + s
    int b = bs / KSEL;
    int pi = idx[bs];
    int gy = pi / 24, gx = pi % 24;
    int t = threadIdx.x, py = t >> 4, px = t & 15;
    size_t src = ((size_t)b * 3 * 384 + gy * 16 + py) * 384 + gx * 16 + px;
    __hip_bfloat16* dst = &selp[(size_t)bs * 768];
#pragma unroll
    for (int c = 0; c < 3; ++c)
        dst[c * 256 + t] = __float2bfloat16(magno[src + (size_t)c * 384 * 384]);
}

// ---------------- fused weight prep: 4 transposes + conv convert ------------
// grid 5328: [0,1296) qkv  [1296,1728) proj  [1728,3456) fc1
//            [3456,5184) fc2  [5184,5328) conv convert (float4)
__global__ __launch_bounds__(256) void prep_weights(
    const float* __restrict__ qkv_w, const float* __restrict__ proj_w,
    const float* __restrict__ fc1_w, const float* __restrict__ fc2_w,
    const float* __restrict__ conv_w,
    __hip_bfloat16* __restrict__ wt_qkv, __hip_bfloat16* __restrict__ wt_proj,
    __hip_bfloat16* __restrict__ wt_fc1, __hip_bfloat16* __restrict__ wt_fc2,
    __hip_bfloat16* __restrict__ convT)
{
    __shared__ float t[32][33];
    int bid = blockIdx.x;
    const float* src;
    __hip_bfloat16* dst;
    int R, C, rem;
    if (bid < 1296)      { src = qkv_w;  dst = wt_qkv;  R = 192; C = 576; rem = bid; }
    else if (bid < 1728) { src = proj_w; dst = wt_proj; R = 192; C = 192; rem = bid - 1296; }
    else if (bid < 3456) { src = fc1_w;  dst = wt_fc1;  R = 192; C = 768; rem = bid - 1728; }
    else if (bid < 5184) { src = fc2_w;  dst = wt_fc2;  R = 768; C = 192; rem = bid - 3456; }
    else {
        int i = (bid - 5184) * 1024 + threadIdx.x * 4;   // 144 blocks x 1024
        float4 v = *reinterpret_cast<const float4*>(&conv_w[i]);
        __hip_bfloat16 o[4] = {__float2bfloat16(v.x), __float2bfloat16(v.y),
                               __float2bfloat16(v.z), __float2bfloat16(v.w)};
        *reinterpret_cast<uint2*>(&convT[i]) = *reinterpret_cast<uint2*>(o);
        return;
    }
    int TR = R / 32, TC = C / 32;
    int l = rem / (TR * TC), r2 = rem % (TR * TC);
    int r0 = (r2 / TC) * 32, c0 = (r2 % TC) * 32;
    size_t lo = (size_t)l * R * C;
    int tx = threadIdx.x & 31, ty = threadIdx.x >> 5;
#pragma unroll
    for (int i = 0; i < 32; i += 8)
        t[ty + i][tx] = src[lo + (size_t)(r0 + ty + i) * C + c0 + tx];
    __syncthreads();
#pragma unroll
    for (int i = 0; i < 32; i += 8)
        dst[lo + (size_t)(c0 + ty + i) * R + r0 + tx] = __float2bfloat16(t[tx][ty + i]);
}

// ---------------- cls token init --------------------------------------------
__global__ void cls_kernel(const float* __restrict__ cls, const float* __restrict__ pos,
                           float* __restrict__ h)
{
    int b = blockIdx.x, t = threadIdx.x;      // 192 threads
    h[(size_t)b * SEQ * DIM + t] = cls[t] + pos[t];
}

// ---------------- LayerNorm over D=192 -> bf16 out (layer-0 ln1 only) -------
__global__ __launch_bounds__(256) void ln_kernel(const float* __restrict__ x,
                                                 const float* __restrict__ s,
                                                 const float* __restrict__ bia,
                                                 __hip_bfloat16* __restrict__ y, int ntok)
{
    int w = threadIdx.x >> 6, lane = threadIdx.x & 63;
    int tok = blockIdx.x * 4 + w;
    if (tok >= ntok) return;
    const float* xp = &x[(size_t)tok * DIM];
    float x0 = xp[lane], x1 = xp[lane + 64], x2 = xp[lane + 128];
    float sum = x0 + x1 + x2;
    for (int off = 32; off; off >>= 1) sum += __shfl_xor(sum, off);
    float mean = sum * (1.f / 192.f);
    float d0 = x0 - mean, d1 = x1 - mean, d2 = x2 - mean;
    float vs = d0 * d0 + d1 * d1 + d2 * d2;
    for (int off = 32; off; off >>= 1) vs += __shfl_xor(vs, off);
    float rs = rsqrtf(vs * (1.f / 192.f) + 1e-6f);
    __hip_bfloat16* yp = &y[(size_t)tok * DIM];
    yp[lane]       = __float2bfloat16(d0 * rs * s[lane]       + bia[lane]);
    yp[lane + 64]  = __float2bfloat16(d1 * rs * s[lane + 64]  + bia[lane + 64]);
    yp[lane + 128] = __float2bfloat16(d2 * rs * s[lane + 128] + bia[lane + 128]);
}

// ---------------- bf16 MFMA GEMM: C = A(M,K)bf16 @ Wt(N,K)bf16^T + bias -----
// MODE 2: gelu -> bf16   MODE 3: patch embed -> f32 h
template <int MODE>
__global__ __launch_bounds__(256) void gemm_bf16(const __hip_bfloat16* __restrict__ A,
                                                 const __hip_bfloat16* __restrict__ Wt,
                                                 const float* __restrict__ bias,
                                                 void* __restrict__ Cout,
                                                 int M, int N, int K,
                                                 const int* __restrict__ selidx,
                                                 const float* __restrict__ pos)
{
    __shared__ __align__(16) char As[8192];   // 64 rows x 64 bf16 (swizzled)
    __shared__ __align__(16) char Bs[8192];
    const int tid = threadIdx.x;
    const int lane = tid & 63, wid = tid >> 6;
    const int wr = wid >> 1, wc = wid & 1;
    const int lr = lane & 15, lk = lane >> 4;
    const int m0 = blockIdx.y * 64, n0 = blockIdx.x * 64;
    f32x4 acc[2][2] = {};

    for (int k0 = 0; k0 < K; k0 += 64) {
#pragma unroll
        for (int it = 0; it < 2; ++it) {
            int chunk = it * 256 + tid;          // 0..511
            int r = chunk >> 3, g = chunk & 7;
            int loff = r * 128 + ((g ^ (r & 7)) * 16);
            *reinterpret_cast<uint4*>(As + loff) =
                *reinterpret_cast<const uint4*>(&A[(size_t)(m0 + r) * K + k0 + g * 8]);
            *reinterpret_cast<uint4*>(Bs + loff) =
                *reinterpret_cast<const uint4*>(&Wt[(size_t)(n0 + r) * K + k0 + g * 8]);
        }
        __syncthreads();
#pragma unroll
        for (int kc = 0; kc < 2; ++kc) {
            int g = kc * 4 + lk;                 // 8-elem k-group within row
            bf16x8 af[2], bfr[2];
#pragma unroll
            for (int mi = 0; mi < 2; ++mi) {
                int r = wr * 32 + mi * 16 + lr;
                af[mi] = *reinterpret_cast<const bf16x8*>(As + r * 128 + ((g ^ (r & 7)) * 16));
            }
#pragma unroll
            for (int ni = 0; ni < 2; ++ni) {
                int r = wc * 32 + ni * 16 + lr;
                bfr[ni] = *reinterpret_cast<const bf16x8*>(Bs + r * 128 + ((g ^ (r & 7)) * 16));
            }
#pragma unroll
            for (int mi = 0; mi < 2; ++mi)
#pragma unroll
                for (int ni = 0; ni < 2; ++ni)
                    acc[mi][ni] = __builtin_amdgcn_mfma_f32_16x16x32_bf16(
                        af[mi], bfr[ni], acc[mi][ni], 0, 0, 0);
        }
        __syncthreads();
    }

#pragma unroll
    for (int mi = 0; mi < 2; ++mi)
#pragma unroll
    for (int ni = 0; ni < 2; ++ni)
#pragma unroll
    for (int j = 0; j < 4; ++j) {
        int row = m0 + wr * 32 + mi * 16 + (lane >> 4) * 4 + j;
        int col = n0 + wc * 32 + ni * 16 + (lane & 15);
        float v = acc[mi][ni][j] + bias[col];
        if (MODE == 2) {
            ((__hip_bfloat16*)Cout)[(size_t)row * N + col] =
                __float2bfloat16(0.5f * v * (1.f + erff(v * 0.70710678118654752f)));
        } else {
            int bb2 = row / KSEL, ss = row % KSEL;
            int pi = selidx[row];
            v += pos[(size_t)(1 + pi) * DIM + col];
            ((float*)Cout)[((size_t)bb2 * SEQ + 1 + ss) * DIM + col] = v;
        }
    }
}

// ---------------- qkv GEMM: N=576; cols<384 -> qk; cols>=384 -> Vt^T --------
__global__ __launch_bounds__(256) void gemm_qkv(const __hip_bfloat16* __restrict__ A,
                                                const __hip_bfloat16* __restrict__ Wt,
                                                const float* __restrict__ bias,
                                                __hip_bfloat16* __restrict__ qk,
                                                __hip_bfloat16* __restrict__ Vt)
{
    __shared__ __align__(16) char As[8192];
    __shared__ __align__(16) char Bs[8192];
    const int tid = threadIdx.x;
    const int lane = tid & 63, wid = tid >> 6;
    const int wr = wid >> 1, wc = wid & 1;
    const int lr = lane & 15, lk = lane >> 4;
    const int m0 = blockIdx.y * 64, n0 = blockIdx.x * 64;
    const int K = DIM;
    f32x4 acc[2][2] = {};

    for (int k0 = 0; k0 < K; k0 += 64) {
#pragma unroll
        for (int it = 0; it < 2; ++it) {
            int chunk = it * 256 + tid;
            int r = chunk >> 3, g = chunk & 7;
            int loff = r * 128 + ((g ^ (r & 7)) * 16);
            *reinterpret_cast<uint4*>(As + loff) =
                *reinterpret_cast<const uint4*>(&A[(size_t)(m0 + r) * K + k0 + g * 8]);
            *reinterpret_cast<uint4*>(Bs + loff) =
                *reinterpret_cast<const uint4*>(&Wt[(size_t)(n0 + r) * K + k0 + g * 8]);
        }
        __syncthreads();
#pragma unroll
        for (int kc = 0; kc < 2; ++kc) {
            int g = kc * 4 + lk;
            bf16x8 af[2], bfr[2];
#pragma unroll
            for (int mi = 0; mi < 2; ++mi) {
                int r = wr * 32 + mi * 16 + lr;
                af[mi] = *reinterpret_cast<const bf16x8*>(As + r * 128 + ((g ^ (r & 7)) * 16));
            }
#pragma unroll
            for (int ni = 0; ni < 2; ++ni) {
                int r = wc * 32 + ni * 16 + lr;
                bfr[ni] = *reinterpret_cast<const bf16x8*>(Bs + r * 128 + ((g ^ (r & 7)) * 16));
            }
#pragma unroll
            for (int mi = 0; mi < 2; ++mi)
#pragma unroll
                for (int ni = 0; ni < 2; ++ni)
                    acc[mi][ni] = __builtin_amdgcn_mfma_f32_16x16x32_bf16(
                        af[mi], bfr[ni], acc[mi][ni], 0, 0, 0);
        }
        __syncthreads();
    }

#pragma unroll
    for (int mi = 0; mi < 2; ++mi)
#pragma unroll
    for (int ni = 0; ni < 2; ++ni)
#pragma unroll
    for (int j = 0; j < 4; ++j) {
        int row = m0 + wr * 32 + mi * 16 + (lane >> 4) * 4 + j;
        int col = n0 + wc * 32 + ni * 16 + (lane & 15);
        float v = acc[mi][ni][j] + bias[col];
        if (col < 384) {
            qk[(size_t)row * 384 + col] = __float2bfloat16(v);
        } else {
            int c = col - 384;
            int b = row / SEQ, s = row - b * SEQ;
            Vt[((size_t)(b * 3 + (c >> 6)) * 64 + (c & 63)) * 160 + s] = __float2bfloat16(v);
        }
    }
}

// ---------------- fused attention + proj + bias + residual + ln2 (R5) -------
__global__ __launch_bounds__(256) void attnproj_kernel(const __hip_bfloat16* __restrict__ qk,
                                                       const __hip_bfloat16* __restrict__ Vt,
                                                       const __hip_bfloat16* __restrict__ Wp,
                                                       const float* __restrict__ pbias,
                                                       float* __restrict__ h,
                                                       const float* __restrict__ ls,
                                                       const float* __restrict__ lb,
                                                       __hip_bfloat16* __restrict__ y)
{
    const int b = blockIdx.y, qt = blockIdx.x;
    const int tid = threadIdx.x;
    const int w = tid >> 6, lane = tid & 63;
    const int lr = lane & 15, lg = lane >> 4;
    __shared__ __hip_bfloat16 Ps[3][32][168];
    __shared__ __hip_bfloat16 Ot[32][200];
    __shared__ float redsum[4][32];
    __shared__ float redsq[4][32];

    const size_t qbase = (size_t)b * SEQ * 384;
    const int q0 = qt * 32;

    if (w < 3) {
        const int hh = w;
        bf16x8 aq[2][2];
#pragma unroll
        for (int mi = 0; mi < 2; ++mi)
#pragma unroll
            for (int ks = 0; ks < 2; ++ks)
                aq[mi][ks] = *reinterpret_cast<const bf16x8*>(
                    &qk[qbase + (size_t)(q0 + mi * 16 + lr) * 384 + hh * 64 + ks * 32 + lg * 8]);
        f32x4 sc[2][10];
#pragma unroll
        for (int mi = 0; mi < 2; ++mi)
#pragma unroll
            for (int nf = 0; nf < 10; ++nf) sc[mi][nf] = (f32x4){0.f, 0.f, 0.f, 0.f};
#pragma unroll
        for (int nf = 0; nf < 10; ++nf) {
            int key = nf * 16 + lr;
#pragma unroll
            for (int ks = 0; ks < 2; ++ks) {
                bf16x8 bk = *reinterpret_cast<const bf16x8*>(
                    &qk[qbase + (size_t)key * 384 + 192 + hh * 64 + ks * 32 + lg * 8]);
#pragma unroll
                for (int mi = 0; mi < 2; ++mi)
                    sc[mi][nf] = __builtin_amdgcn_mfma_f32_16x16x32_bf16(
                        aq[mi][ks], bk, sc[mi][nf], 0, 0, 0);
            }
        }
#pragma unroll
        for (int mi = 0; mi < 2; ++mi) {
            float mx[4] = {-1e30f, -1e30f, -1e30f, -1e30f};
#pragma unroll
            for (int nf = 0; nf < 10; ++nf) {
                bool valid = nf * 16 + lr < SEQ;
#pragma unroll
                for (int j = 0; j < 4; ++j) {
                    float v = valid ? sc[mi][nf][j] * 0.125f : -1e30f;
                    sc[mi][nf][j] = v;
                    mx[j] = fmaxf(mx[j], v);
                }
            }
#pragma unroll
            for (int j = 0; j < 4; ++j)
                for (int off = 1; off < 16; off <<= 1)
                    mx[j] = fmaxf(mx[j], __shfl_xor(mx[j], off));
            float sm[4] = {0.f, 0.f, 0.f, 0.f};
#pragma unroll
            for (int nf = 0; nf < 10; ++nf)
#pragma unroll
                for (int j = 0; j < 4; ++j) {
                    float p = __expf(sc[mi][nf][j] - mx[j]);
                    sc[mi][nf][j] = p;
                    sm[j] += p;
                }
#pragma unroll
            for (int j = 0; j < 4; ++j) {
                for (int off = 1; off < 16; off <<= 1) sm[j] += __shfl_xor(sm[j], off);
                sm[j] = 1.f / sm[j];
            }
#pragma unroll
            for (int nf = 0; nf < 10; ++nf) {
                int key = nf * 16 + lr;
#pragma unroll
                for (int j = 0; j < 4; ++j)
                    Ps[hh][mi * 16 + lg * 4 + j][key] = __float2bfloat16(sc[mi][nf][j] * sm[j]);
            }
        }
        const __hip_bfloat16* vtb = &Vt[(size_t)(b * 3 + hh) * 64 * 160];
        f32x4 oacc[2][4];
#pragma unroll
        for (int mi = 0; mi < 2; ++mi)
#pragma unroll
            for (int nf = 0; nf < 4; ++nf) oacc[mi][nf] = (f32x4){0.f, 0.f, 0.f, 0.f};
#pragma unroll
        for (int ks = 0; ks < 5; ++ks) {
            bf16x8 ap[2];
            ap[0] = *reinterpret_cast<const bf16x8*>(&Ps[hh][lr][ks * 32 + lg * 8]);
            ap[1] = *reinterpret_cast<const bf16x8*>(&Ps[hh][16 + lr][ks * 32 + lg * 8]);
#pragma unroll
            for (int nf = 0; nf < 4; ++nf) {
                bf16x8 bv = *reinterpret_cast<const bf16x8*>(
                    &vtb[(size_t)(nf * 16 + lr) * 160 + ks * 32 + lg * 8]);
#pragma unroll
                for (int mi = 0; mi < 2; ++mi)
                    oacc[mi][nf] = __builtin_amdgcn_mfma_f32_16x16x32_bf16(
                        ap[mi], bv, oacc[mi][nf], 0, 0, 0);
            }
        }
#pragma unroll
        for (int mi = 0; mi < 2; ++mi)
#pragma unroll
            for (int nf = 0; nf < 4; ++nf)
#pragma unroll
                for (int j = 0; j < 4; ++j)
                    Ot[mi * 16 + lg * 4 + j][hh * 64 + nf * 16 + lr] =
                        __float2bfloat16(oacc[mi][nf][j]);
    }
    __syncthreads();

    f32x4 pacc[2][3];
#pragma unroll
    for (int mi = 0; mi < 2; ++mi)
#pragma unroll
        for (int nf = 0; nf < 3; ++nf) pacc[mi][nf] = (f32x4){0.f, 0.f, 0.f, 0.f};
#pragma unroll
    for (int kk = 0; kk < 6; ++kk) {
        bf16x8 af[2];
        af[0] = *reinterpret_cast<const bf16x8*>(&Ot[lr][kk * 32 + lg * 8]);
        af[1] = *reinterpret_cast<const bf16x8*>(&Ot[16 + lr][kk * 32 + lg * 8]);
#pragma unroll
        for (int nf = 0; nf < 3; ++nf) {
            int ncol = w * 48 + nf * 16 + lr;
            bf16x8 bw = *reinterpret_cast<const bf16x8*>(&Wp[(size_t)ncol * 192 + kk * 32 + lg * 8]);
#pragma unroll
            for (int mi = 0; mi < 2; ++mi)
                pacc[mi][nf] = __builtin_amdgcn_mfma_f32_16x16x32_bf16(
                    af[mi], bw, pacc[mi][nf], 0, 0, 0);
        }
    }
    float v[2][3][4];
    float psum[2][4] = {}, psq[2][4] = {};
#pragma unroll
    for (int mi = 0; mi < 2; ++mi)
#pragma unroll
    for (int nf = 0; nf < 3; ++nf) {
        int col = w * 48 + nf * 16 + lr;
        float bcol = pbias[col];
#pragma unroll
        for (int j = 0; j < 4; ++j) {
            int q = q0 + mi * 16 + lg * 4 + j;
            float res = (q < SEQ) ? h[((size_t)b * SEQ + q) * DIM + col] : 0.f;
            float t = pacc[mi][nf][j] + bcol + res;
            v[mi][nf][j] = t;
            psum[mi][j] += t;
            psq[mi][j] += t * t;
        }
    }
#pragma unroll
    for (int mi = 0; mi < 2; ++mi)
#pragma unroll
        for (int j = 0; j < 4; ++j) {
            for (int off = 1; off < 16; off <<= 1) {
                psum[mi][j] += __shfl_xor(psum[mi][j], off);
                psq[mi][j]  += __shfl_xor(psq[mi][j], off);
            }
            redsum[w][mi * 16 + lg * 4 + j] = psum[mi][j];
            redsq[w][mi * 16 + lg * 4 + j]  = psq[mi][j];
        }
    __syncthreads();
#pragma unroll
    for (int mi = 0; mi < 2; ++mi) {
#pragma unroll
        for (int j = 0; j < 4; ++j) {
            int r = mi * 16 + lg * 4 + j;
            int q = q0 + r;
            if (q >= SEQ) continue;
            float tsum = redsum[0][r] + redsum[1][r] + redsum[2][r] + redsum[3][r];
            float tsq  = redsq[0][r]  + redsq[1][r]  + redsq[2][r]  + redsq[3][r];
            float mean = tsum * (1.f / 192.f);
            float var  = tsq * (1.f / 192.f) - mean * mean;
            float rs = rsqrtf(var + 1e-6f);
#pragma unroll
            for (int nf = 0; nf < 3; ++nf) {
                int col = w * 48 + nf * 16 + lr;
                float t = v[mi][nf][j];
                h[((size_t)b * SEQ + q) * DIM + col] = t;
                y[((size_t)b * SEQ + q) * DIM + col] =
                    __float2bfloat16((t - mean) * rs * ls[col] + lb[col]);
            }
        }
    }
}

// ---------------- fc2 + bias + residual + LN (round-5 version) --------------
template <bool DO_LN>
__global__ __launch_bounds__(256) void gemm_res_ln(const __hip_bfloat16* __restrict__ A,
                                                   const __hip_bfloat16* __restrict__ Wt,
                                                   const float* __restrict__ bias,
                                                   float* __restrict__ h,
                                                   const float* __restrict__ ls,
                                                   const float* __restrict__ lb,
                                                   __hip_bfloat16* __restrict__ y,
                                                   int K)
{
    __shared__ __align__(16) char As[8192];    // 64 x 64 bf16 swizzled
    __shared__ __align__(16) char Bs[24576];   // 192 x 64 bf16 swizzled
    const int tid = threadIdx.x;
    const int lane = tid & 63, w = tid >> 6;
    const int lr = lane & 15, lg = lane >> 4;
    const int m0 = blockIdx.x * 64;
    f32x4 acc[12] = {};

    for (int k0 = 0; k0 < K; k0 += 64) {
        {
            int chunk = tid;
#pragma unroll
            for (int it = 0; it < 2; ++it, chunk += 256) {
                int r = chunk >> 3, g = chunk & 7;
                *reinterpret_cast<uint4*>(As + r * 128 + ((g ^ (r & 7)) * 16)) =
                    *reinterpret_cast<const uint4*>(&A[(size_t)(m0 + r) * K + k0 + g * 8]);
            }
        }
        {
            int chunk = tid;
#pragma unroll
            for (int it = 0; it < 6; ++it, chunk += 256) {
                int r = chunk >> 3, g = chunk & 7;
                *reinterpret_cast<uint4*>(Bs + r * 128 + ((g ^ (r & 7)) * 16)) =
                    *reinterpret_cast<const uint4*>(&Wt[(size_t)r * K + k0 + g * 8]);
            }
        }
        __syncthreads();
#pragma unroll
        for (int kc = 0; kc < 2; ++kc) {
            int g = kc * 4 + lg;
            int ar = w * 16 + lr;
            bf16x8 af = *reinterpret_cast<const bf16x8*>(As + ar * 128 + ((g ^ (ar & 7)) * 16));
#pragma unroll
            for (int nf = 0; nf < 12; ++nf) {
                int br = nf * 16 + lr;
                bf16x8 bfv = *reinterpret_cast<const bf16x8*>(Bs + br * 128 + ((g ^ (br & 7)) * 16));
                acc[nf] = __builtin_amdgcn_mfma_f32_16x16x32_bf16(af, bfv, acc[nf], 0, 0, 0);
            }
        }
        __syncthreads();
    }

    float v[12][4];
    float sum[4] = {0.f, 0.f, 0.f, 0.f};
#pragma unroll
    for (int nf = 0; nf < 12; ++nf) {
        int col = nf * 16 + lr;
#pragma unroll
        for (int j = 0; j < 4; ++j) {
            int row = m0 + w * 16 + lg * 4 + j;
            float t = acc[nf][j] + bias[col] + h[(size_t)row * DIM + col];
            v[nf][j] = t;
            h[(size_t)row * DIM + col] = t;
            sum[j] += t;
        }
    }
    if (DO_LN) {
#pragma unroll
        for (int j = 0; j < 4; ++j)
            for (int off = 1; off < 16; off <<= 1) sum[j] += __shfl_xor(sum[j], off);
        float mean[4], sq[4] = {0.f, 0.f, 0.f, 0.f};
#pragma unroll
        for (int j = 0; j < 4; ++j) mean[j] = sum[j] * (1.f / 192.f);
#pragma unroll
        for (int nf = 0; nf < 12; ++nf)
#pragma unroll
            for (int j = 0; j < 4; ++j) {
                float d = v[nf][j] - mean[j];
                sq[j] += d * d;
            }
#pragma unroll
        for (int j = 0; j < 4; ++j) {
            for (int off = 1; off < 16; off <<= 1) sq[j] += __shfl_xor(sq[j], off);
            sq[j] = rsqrtf(sq[j] * (1.f / 192.f) + 1e-6f);
        }
#pragma unroll
        for (int nf = 0; nf < 12; ++nf) {
            int col = nf * 16 + lr;
            float sc = ls[col], bc = lb[col];
#pragma unroll
            for (int j = 0; j < 4; ++j) {
                int row = m0 + w * 16 + lg * 4 + j;
                y[(size_t)row * DIM + col] =
                    __float2bfloat16((v[nf][j] - mean[j]) * sq[j] * sc + bc);
            }
        }
    }
}

// ---------------- head: final LN of cls + (64,192)@(192,1000) ---------------
__global__ __launch_bounds__(256) void head_kernel(const float* __restrict__ h,
                                                   const float* __restrict__ nfs,
                                                   const float* __restrict__ nfb,
                                                   const float* __restrict__ hw,
                                                   const float* __restrict__ hb,
                                                   float* __restrict__ out)
{
    int b = blockIdx.x, t = threadIdx.x;
    __shared__ float y[DIM];
    __shared__ float red[4];
    float x = (t < DIM) ? h[(size_t)b * SEQ * DIM + t] : 0.f;
    float sum = x;
    for (int off = 32; off; off >>= 1) sum += __shfl_xor(sum, off);
    if ((t & 63) == 0) red[t >> 6] = sum;
    __syncthreads();
    float mean = (red[0] + red[1] + red[2] + red[3]) * (1.f / 192.f);
    __syncthreads();
    float d = (t < DIM) ? (x - mean) : 0.f;
    float v = d * d;
    for (int off = 32; off; off >>= 1) v += __shfl_xor(v, off);
    if ((t & 63) == 0) red[t >> 6] = v;
    __syncthreads();
    float var = (red[0] + red[1] + red[2] + red[3]) * (1.f / 192.f);
    float rs = rsqrtf(var + 1e-6f);
    if (t < DIM) y[t] = d * rs * nfs[t] + nfb[t];
    __syncthreads();
    for (int n = t; n < 1000; n += 256) {
        float acc = hb[n];
#pragma unroll 8
        for (int k = 0; k < DIM; ++k)
            acc = fmaf(y[k], hw[(size_t)k * 1000 + n], acc);
        out[(size_t)b * 1000 + n] = acc;
    }
}

// ---------------------------------------------------------------------------
extern "C" void kernel_launch(void* const* d_in, const int* in_sizes, int n_in,
                              void* d_out, int out_size, void* d_ws, size_t ws_size,
                              hipStream_t stream)
{
    const float* magno  = (const float*)d_in[0];
    const float* line   = (const float*)d_in[1];
    const float* conv_w = (const float*)d_in[2];
    const float* conv_b = (const float*)d_in[3];
    const float* pos    = (const float*)d_in[4];
    const float* cls    = (const float*)d_in[5];
    const float* ln1_s  = (const float*)d_in[6];
    const float* ln1_b  = (const float*)d_in[7];
    const float* qkv_w  = (const float*)d_in[8];
    const float* qkv_b  = (const float*)d_in[9];
    const float* proj_w = (const float*)d_in[10];
    const float* proj_b = (const float*)d_in[11];
    const float* ln2_s  = (const float*)d_in[12];
    const float* ln2_b  = (const float*)d_in[13];
    const float* fc1_w  = (const float*)d_in[14];
    const float* fc1_b  = (const float*)d_in[15];
    const float* fc2_w  = (const float*)d_in[16];
    const float* fc2_b  = (const float*)d_in[17];
    const float* normf_s = (const float*)d_in[18];
    const float* normf_b = (const float*)d_in[19];
    const float* head_w = (const float*)d_in[20];
    const float* head_b = (const float*)d_in[21];
    float* out = (float*)d_out;
    (void)in_sizes; (void)n_in; (void)out_size; (void)ws_size;

    // workspace layout (bytes)
    char* ws = (char*)d_ws;
    int*            idx     = (int*)            (ws + 0);         //    36864 (pad)
    float*          h       = (float*)          (ws + 147456);    //  7127040
    __hip_bfloat16* y       = (__hip_bfloat16*) (ws + 7274496);   //  3563520
    __hip_bfloat16* qk      = (__hip_bfloat16*) (ws + 10838016);  //  7127040
    __hip_bfloat16* Vt      = (__hip_bfloat16*) (ws + 17965056);  //  3932160
    __hip_bfloat16* tbuf    = (__hip_bfloat16*) (ws + 21897216);  // 14254080
    __hip_bfloat16* wt_qkv  = (__hip_bfloat16*) (ws + 36151296);  //  2654208
    __hip_bfloat16* wt_proj = (__hip_bfloat16*) (ws + 38805504);  //   884736
    __hip_bfloat16* wt_fc1  = (__hip_bfloat16*) (ws + 39690240);  //  3538944
    __hip_bfloat16* wt_fc2  = (__hip_bfloat16*) (ws + 43229184);  //  3538944
    float*          scoresbuf = (float*)qk;             // alias (used before qk)
    __hip_bfloat16* convT     = y;                      // alias (used before y)
    __hip_bfloat16* selp      = tbuf;                   // alias

    // ---- prep: weights -> bf16 [N][K] (one kernel); zero Vt pads once ----
    hipMemsetAsync(Vt, 0, 3932160, stream);
    prep_weights<<<5328, 256, 0, stream>>>(qkv_w, proj_w, fc1_w, fc2_w, conv_w,
                                           wt_qkv, wt_proj, wt_fc1, wt_fc2, convT);

    // ---- patch selection + embed ----
    scores_kernel<<<Bsz * NPATCH / 4, 256, 0, stream>>>(line, scoresbuf);
    topk_kernel<<<Bsz, 256, 0, stream>>>(scoresbuf, idx);
    gather_kernel<<<Bsz * KSEL, 256, 0, stream>>>(magno, idx, selp);
    cls_kernel<<<Bsz, DIM, 0, stream>>>(cls, pos, h);
    gemm_bf16<3><<<dim3(3, 144), 256, 0, stream>>>(selp, convT, conv_b, h,
                                                   9216, DIM, 768, idx, pos);

    const int ntok = Bsz * SEQ;              // 9280 = 145*64
    ln_kernel<<<ntok / 4, 256, 0, stream>>>(h, ln1_s, ln1_b, y, ntok);
    for (int l = 0; l < 12; ++l) {
        gemm_qkv<<<dim3(9, 145), 256, 0, stream>>>(y, wt_qkv + (size_t)l * 576 * DIM,
                                                   qkv_b + l * 576, qk, Vt);
        attnproj_kernel<<<dim3(5, Bsz), 256, 0, stream>>>(qk, Vt,
                                                          wt_proj + (size_t)l * DIM * DIM,
                                                          proj_b + l * DIM, h,
                                                          ln2_s + l * DIM, ln2_b + l * DIM, y);
        gemm_bf16<2><<<dim3(12, 145), 256, 0, stream>>>(y, wt_fc1 + (size_t)l * HIDN * DIM,
                                                        fc1_b + l * HIDN, tbuf,
                                                        ntok, HIDN, DIM, nullptr, nullptr);
        if (l < 11)
            gemm_res_ln<true><<<145, 256, 0, stream>>>(
                tbuf, wt_fc2 + (size_t)l * DIM * HIDN, fc2_b + l * DIM, h,
                ln1_s + (l + 1) * DIM, ln1_b + (l + 1) * DIM, y, HIDN);
        else
            gemm_res_ln<false><<<145, 256, 0, stream>>>(
                tbuf, wt_fc2 + (size_t)l * DIM * HIDN, fc2_b + l * DIM, h,
                nullptr, nullptr, y, HIDN);
    }
    head_kernel<<<Bsz, 256, 0, stream>>>(h, normf_s, normf_b, head_w, head_b, out);
}